// Round 5
// baseline (283.398 us; speedup 1.0000x reference)
//
#include <hip/hip_runtime.h>

// CTC batch loss (keras ctc_batch_cost), B=256, T=512, C=256, U=64.
// Producer/consumer wave specialization, one block (256 thr, 4 waves) per
// batch element:
//   wave 0  : serial CTC forward recurrence. Lane l owns extended states 2l
//             (blank) and 2l+1 (label l); lane 63 also owns state 128 (its
//             s-1 neighbor is its own odd register -> one DPP shr per step).
//             Linear domain + wave-uniform power-of-2 rescale every 8 steps
//             (target 2^60). LDS gathers prefetched 4 steps ahead.
//   waves 1-3: stream y_pred rows (1 KB each, one global_load_dwordx4 per
//             wave per row) into a 3-chunk LDS ring (48 KB), 16 rows per
//             chunk, __syncthreads per chunk. Producers run 2 chunks ahead;
//             consumer overshoot-prefetch reads at most 1 chunk ahead.
// t=0 init is folded into the recurrence by seeding a_even = (lane==0).

constexpr int B = 256, T = 512, C = 256, U = 64;
constexpr int CH = 16, NCH = T / CH;          // 32 chunks
#define EPSF 1e-7f

__device__ __forceinline__ float dpp_wave_shr1(float x) {
    // previous lane's value; lane 0 -> 0 (bound_ctrl)
    return __int_as_float(__builtin_amdgcn_update_dpp(
        0, __float_as_int(x), 0x138, 0xf, 0xf, true));
}

#define DPPMAX(ctrl)                                                      \
    {                                                                     \
        float x_ = __int_as_float(__builtin_amdgcn_update_dpp(            \
            0, __float_as_int(m_), (ctrl), 0xf, 0xf, true));              \
        m_ = fmaxf(m_, x_);                                               \
    }

#define RESCALE()                                                         \
    {                                                                     \
        float m_ = fmaxf(fmaxf(a_even, a_odd), a_top);                    \
        DPPMAX(0x111) DPPMAX(0x112) DPPMAX(0x114) DPPMAX(0x118)           \
        DPPMAX(0x142) DPPMAX(0x143)                                       \
        const float mx_ = __int_as_float(                                 \
            __builtin_amdgcn_readlane(__float_as_int(m_), 63));           \
        int e_ = (__float_as_int(mx_) >> 23) & 0xff;                      \
        int k_ = 187 - e_;                                                \
        k_ = k_ > 127 ? 127 : k_;                                         \
        const float s_ = __int_as_float((k_ + 127) << 23);                \
        a_even *= s_; a_odd *= s_; a_top *= s_;                           \
        esum += k_;                                                       \
    }

__global__ __launch_bounds__(256, 1) void ctc_kernel(const int* __restrict__ y_true,
                                                     const float* __restrict__ y_pred,
                                                     float* __restrict__ out) {
    __shared__ float lds[3 * CH * C];         // 48 KB ring, slot = chunk % 3
    const int b = blockIdx.x;
    const int lane = threadIdx.x & 63;
    const int wid = threadIdx.x >> 6;
    const float* __restrict__ rowp = y_pred + (size_t)b * T * C;

    if (wid) {
        // ------------------------- producers (waves 1..3) ----------------
        const int pw = wid - 1;               // 0..2; rows j with j%3 == pw
        // Prologue: chunks 0,1 -> slots 0,1
#pragma unroll 1
        for (int c = 0; c < 2; ++c) {
            float4 g[6];
#pragma unroll
            for (int n = 0; n < 6; ++n) {
                const int j = pw + 3 * n;
                if (j < CH) g[n] = ((const float4*)(rowp + (size_t)(c * CH + j) * C))[lane];
            }
#pragma unroll
            for (int n = 0; n < 6; ++n) {
                const int j = pw + 3 * n;
                if (j < CH) ((float4*)&lds[(c * CH + j) * C])[lane] = g[n];
            }
        }
        __syncthreads();
        int ws = 2;                            // slot of chunk k+2
#pragma unroll 1
        for (int k = 0; k < NCH; ++k) {
            const int c = k + 2;
            if (c < NCH) {
                float4 g[6];
#pragma unroll
                for (int n = 0; n < 6; ++n) {
                    const int j = pw + 3 * n;
                    if (j < CH) g[n] = ((const float4*)(rowp + (size_t)(c * CH + j) * C))[lane];
                }
#pragma unroll
                for (int n = 0; n < 6; ++n) {
                    const int j = pw + 3 * n;
                    if (j < CH) ((float4*)&lds[(ws * CH + j) * C])[lane] = g[n];
                }
            }
            __syncthreads();
            ws = ws + 1; if (ws == 3) ws = 0;
        }
    } else {
        // --------------------------- consumer (wave 0) -------------------
        const int label = y_true[b * U + lane];
        const int label_prev = __shfl_up(label, 1);
        const bool skip_ok = (lane > 0) && (label != label_prev);
        __syncthreads();                       // chunks 0,1 visible

        float plab[4], pblk[4];
#pragma unroll
        for (int t = 0; t < 4; ++t) {          // warm rows 0..3 (slot 0)
            plab[t] = lds[t * C + label];
            pblk[t] = lds[t * C + (C - 1)];
        }
        // Seed so that applying the recurrence at t=0 yields alpha0 exactly.
        float a_even = (lane == 0) ? 1.f : 0.f, a_odd = 0.f, a_top = 0.f;
        int esum = 0, cs = 0;
#pragma unroll 1
        for (int k = 0; k < NCH; ++k) {
            int ns = cs + 1; if (ns == 3) ns = 0;
#pragma unroll
            for (int i = 0; i < CH; ++i) {
                const int t = k * CH + i;
                const float pb = pblk[i & 3] + EPSF;   // row t
                const float pl = plab[i & 3] + EPSF;
                // prefetch row t+4 (clamped; clamp only hits at k=31, i>=12)
                {
                    int srow = (i < 12) ? (cs * CH + i + 4) : (ns * CH + (i - 12));
                    if (t + 4 >= T) srow = cs * CH + 15;
                    plab[i & 3] = lds[srow * C + label];
                    pblk[i & 3] = lds[srow * C + (C - 1)];
                }
                const float po = dpp_wave_shr1(a_odd); // alpha[2l-1]
                const float skp = skip_ok ? po : 0.f;
                const float ne = (a_even + po) * pb;
                const float no = (a_even + a_odd + skp) * pl;
                const float nt = (a_top + a_odd) * pb;
                a_even = ne; a_odd = no; a_top = nt;
                if ((t & 7) == 7) RESCALE();
            }
            __syncthreads();
            cs = ns;
        }
        // loss = -ln(alpha[128] + alpha[127]); stored = true * 2^esum
        if (lane == 63)
            out[b] = -logf(a_top + a_odd) + (float)esum * 0.69314718055994531f;
    }
}

extern "C" void kernel_launch(void* const* d_in, const int* in_sizes, int n_in,
                              void* d_out, int out_size, void* d_ws, size_t ws_size,
                              hipStream_t stream) {
    const int* y_true   = (const int*)d_in[0];
    const float* y_pred = (const float*)d_in[1];
    float* out = (float*)d_out;
    hipLaunchKernelGGL(ctc_kernel, dim3(B), dim3(256), 0, stream,
                       y_true, y_pred, out);
}

// Round 6
// 225.680 us; speedup vs baseline: 1.2558x; 1.2558x over previous
//
#include <hip/hip_runtime.h>

// CTC batch loss (keras ctc_batch_cost), B=256, T=512, C=256, U=64.
// Two-phase:
//  Phase 1 (gather_kernel, 2048 blocks x 256 thr): parallel gather-transpose.
//    Each wave loads full 1KB y_pred rows coalesced (one dwordx4/lane),
//    stages through a per-wave LDS buffer, writes the 65 needed words
//    (label probs 0..63, blank at 64) to compact [B][T][68] in d_ws.
//  Phase 2 (chain_kernel<68,true>, 256 blocks x 64 thr): serial CTC forward
//    recurrence, one wave per batch. Lane l owns extended states 2l (blank)
//    and 2l+1 (label l); lane 63 also owns state 128 (s-1 neighbor is its
//    own odd register -> one DPP shr per step). Linear domain, wave-uniform
//    power-of-2 rescale every 8 steps (target 2^60). Per step: ONE coalesced
//    load (lane l -> compact[t*68+l]) + ONE wave-uniform broadcast load
//    (compact[t*68+64]) -> ~3 memory transactions vs 17 for raw gathers.
//    Chunked register double-buffering (16-step chunks, next chunk's loads
//    issued before computing current; sched_barrier keeps them hoisted).
// Fallback (ws too small): chain_kernel<C,false> gathers straight from
// y_pred (the R4 structure, ~67 us) -- same math, slower loads.

constexpr int B = 256, T = 512, C = 256, U = 64;
constexpr int CH = 16;
constexpr int STR = 68;                    // compact row stride (words)
#define EPSF 1e-7f

__device__ __forceinline__ float dpp_wave_shr1(float x) {
    // previous lane's value; lane 0 -> 0 (bound_ctrl)
    return __int_as_float(__builtin_amdgcn_update_dpp(
        0, __float_as_int(x), 0x138, 0xf, 0xf, true));
}

#define DPPMAX(ctrl)                                                      \
    {                                                                     \
        float x_ = __int_as_float(__builtin_amdgcn_update_dpp(            \
            0, __float_as_int(m_), (ctrl), 0xf, 0xf, true));              \
        m_ = fmaxf(m_, x_);                                               \
    }

#define RESCALE()                                                         \
    {                                                                     \
        float m_ = fmaxf(fmaxf(a_even, a_odd), a_top);                    \
        DPPMAX(0x111) DPPMAX(0x112) DPPMAX(0x114) DPPMAX(0x118)           \
        DPPMAX(0x142) DPPMAX(0x143)                                       \
        const float mx_ = __int_as_float(                                 \
            __builtin_amdgcn_readlane(__float_as_int(m_), 63));           \
        int e_ = (__float_as_int(mx_) >> 23) & 0xff;                      \
        int k_ = 187 - e_;                                                \
        k_ = k_ > 127 ? 127 : k_;                                         \
        const float s_ = __int_as_float((k_ + 127) << 23);                \
        a_even *= s_; a_odd *= s_; a_top *= s_;                           \
        esum += k_;                                                       \
    }

// Load chunk c (t = c*CH + i) into named register arrays.
#define LOAD_CHUNK(LA, BL, cidx, LP, BP, STRIDE)                          \
    {                                                                     \
        const int c_ = (cidx);                                            \
        _Pragma("unroll")                                                 \
        for (int i = 0; i < CH; ++i) {                                    \
            int t = c_ * CH + i;                                          \
            t = t < T ? t : T - 1;                                        \
            LA[i] = LP[(size_t)t * STRIDE];                               \
            BL[i] = BP[(size_t)t * STRIDE];                               \
        }                                                                 \
    }

#define COMP_CHUNK(LA, BL, cidx)                                          \
    {                                                                     \
        const int c_ = (cidx);                                            \
        _Pragma("unroll")                                                 \
        for (int i = 0; i < CH; ++i) {                                    \
            const int t = c_ * CH + i;                                    \
            const float pb = BL[i] + EPSF;                                \
            const float pl = LA[i] + EPSF;                                \
            const float po = dpp_wave_shr1(a_odd);                        \
            const float skp = skip_ok ? po : 0.f;                         \
            const float ne = (a_even + po) * pb;                          \
            const float no = (a_even + a_odd + skp) * pl;                 \
            const float nt = (a_top + a_odd) * pb;                        \
            a_even = ne; a_odd = no; a_top = nt;                          \
            if ((t & 7) == 7) RESCALE();                                  \
        }                                                                 \
    }

// ---------------- Phase 1: gather-transpose ----------------
__global__ __launch_bounds__(256) void gather_kernel(const int* __restrict__ y_true,
                                                     const float* __restrict__ y_pred,
                                                     float* __restrict__ compact) {
    __shared__ float buf[4][2][C];         // per-wave double buffer (8 KB)
    const int lane = threadIdx.x & 63;
    const int w = threadIdx.x >> 6;
    const int g = blockIdx.x;              // 2048 blocks
    const int b = g >> 3;                  // 8 blocks per batch
    const int r0 = (g & 7) * 64 + w;       // rows r0 + 4*i, i = 0..15
    const int lab = y_true[b * U + lane];
    const float* __restrict__ rp = y_pred + (size_t)b * T * C;
    float* __restrict__ cp = compact + (size_t)b * T * STR;

    float4 v = ((const float4*)(rp + (size_t)r0 * C))[lane];
#pragma unroll
    for (int i = 0; i < 16; ++i) {
        const int r = r0 + 4 * i;
        float4 vn = v;
        if (i < 15) vn = ((const float4*)(rp + (size_t)(r + 4) * C))[lane];
        float* bb = &buf[w][i & 1][0];
        ((float4*)bb)[lane] = v;           // stage row in LDS (in-order per wave)
        const float sel = bb[lab];         // compiler inserts lgkmcnt wait
        cp[(size_t)r * STR + lane] = sel;
        if (lane == 0) cp[(size_t)r * STR + 64] = bb[C - 1];   // blank
        v = vn;
    }
}

// ---------------- Phase 2: serial chain ----------------
template <int STRIDE, bool COMPACT>
__global__ __launch_bounds__(64) void chain_kernel(const int* __restrict__ y_true,
                                                   const float* __restrict__ src,
                                                   float* __restrict__ out) {
    const int b = blockIdx.x;
    const int lane = threadIdx.x;
    const int label = y_true[b * U + lane];
    const int label_prev = __shfl_up(label, 1);
    const bool skip_ok = (lane > 0) && (label != label_prev);
    const float* __restrict__ base = src + (size_t)b * T * STRIDE;
    const float* __restrict__ labp = COMPACT ? (base + lane) : (base + label);
    const float* __restrict__ blkp = COMPACT ? (base + 64) : (base + (C - 1));

    // Seed so applying the recurrence at t=0 yields alpha0 exactly.
    float a_even = (lane == 0) ? 1.f : 0.f, a_odd = 0.f, a_top = 0.f;
    int esum = 0;

    float la0[CH], bl0[CH], la1[CH], bl1[CH];
    LOAD_CHUNK(la0, bl0, 0, labp, blkp, STRIDE);     // chunk 0: t = 0..15

    for (int c2 = 0; c2 < 16; ++c2) {                // 32 chunks, 2 per iter
        const int c = 2 * c2;
        LOAD_CHUNK(la1, bl1, c + 1, labp, blkp, STRIDE);
        __builtin_amdgcn_sched_barrier(0);
        COMP_CHUNK(la0, bl0, c);
        if (c2 < 15) LOAD_CHUNK(la0, bl0, c + 2, labp, blkp, STRIDE);
        __builtin_amdgcn_sched_barrier(0);
        COMP_CHUNK(la1, bl1, c + 1);
    }

    // loss = -ln(alpha[128] + alpha[127]); stored = true * 2^esum
    if (lane == 63)
        out[b] = -logf(a_top + a_odd) + (float)esum * 0.69314718055994531f;
}

extern "C" void kernel_launch(void* const* d_in, const int* in_sizes, int n_in,
                              void* d_out, int out_size, void* d_ws, size_t ws_size,
                              hipStream_t stream) {
    const int* y_true   = (const int*)d_in[0];
    const float* y_pred = (const float*)d_in[1];
    float* out = (float*)d_out;
    const size_t need = (size_t)B * T * STR * sizeof(float);   // ~34.6 MB
    if (ws_size >= need) {
        float* compact = (float*)d_ws;
        hipLaunchKernelGGL(gather_kernel, dim3(2048), dim3(256), 0, stream,
                           y_true, y_pred, compact);
        hipLaunchKernelGGL((chain_kernel<STR, true>), dim3(B), dim3(64), 0, stream,
                           y_true, compact, out);
    } else {
        hipLaunchKernelGGL((chain_kernel<C, false>), dim3(B), dim3(64), 0, stream,
                           y_true, y_pred, out);
    }
}